// Round 1
// baseline (390.630 us; speedup 1.0000x reference)
//
#include <hip/hip_runtime.h>
#include <cstddef>

#define T_STEPS 256
#define OBS     32
#define ACTD    8
#define DXT     40      // OBS+ACT
#define HDIM    64
#define NB      16      // sequences per block
#define APAD    132     // A row stride in f16 elems (k dim padded 128 -> 132)
#define NSEQ    4096
#define NELM    (NB*DXT) // 640 x-elements staged per step per block

typedef _Float16 f16x8 __attribute__((ext_vector_type(8)));
typedef _Float16 f16x4 __attribute__((ext_vector_type(4)));
typedef float    f32x4 __attribute__((ext_vector_type(4)));

union F8 { f16x8 v; f16x4 q[2]; _Float16 e[8]; };

__device__ __forceinline__ float fsig(float x) {
    // 1/(1+exp(-x)); graceful at +-inf
    return __builtin_amdgcn_rcpf(1.0f + __expf(-x));
}
__device__ __forceinline__ float ftanh(float x) {
    // tanh(x) = 1 - 2/(exp(2x)+1); exp overflow -> inf -> rcp -> 0 -> 1 (correct)
    return 1.0f - 2.0f * __builtin_amdgcn_rcpf(__expf(2.0f * x) + 1.0f);
}

// Load one 16x32 A-fragment (8 f16/lane): elems 0-3 at k=kc+4g+j, elems 4-7 at k+16.
__device__ __forceinline__ f16x8 ldfrag(const _Float16* __restrict__ A, int r, int g, int kc) {
    const _Float16* p = A + r * APAD + kc + 4 * g;
    F8 u;
    u.q[0] = *(const f16x4*)(p);
    u.q[1] = *(const f16x4*)(p + 16);
    return u.v;
}

__global__ __launch_bounds__(256, 1)
void lstm_fused(const float* __restrict__ obss, const float* __restrict__ actions,
                const float* __restrict__ W, const float* __restrict__ b,
                const float* __restrict__ Wdec, const float* __restrict__ bdec_p,
                float* __restrict__ out)
{
    // A layout (per seq row): k 0..63 = h units, k 64..103 = x dims, k 104..131 = zero pad
    __shared__ _Float16 Ahi[2][NB * APAD];
    __shared__ _Float16 Alo[2][NB * APAD];
    __shared__ float    partb[2][64];   // [buf][wave*16 + seq] decode partials

    const int tid  = threadIdx.x;
    const int w    = tid >> 6;          // wave 0..3
    const int lane = tid & 63;
    const int g    = lane >> 4;         // k-group 0..3
    const int m    = lane & 15;
    const int u    = 16 * w + m;        // hidden unit this lane updates
    const int n0   = blockIdx.x * NB;

    // ---- one-time: preload W fragments into registers (f16 hi/lo split) ----
    // wave w computes gate cols {64e + 16w + m}, e=0..3  => unit u for all 4 gates
    f16x8 Bhh[4][2], Bhl[4][2], Bxh[4][2];
    {
        const float* Wc = W + (16 * w + m);
#pragma unroll
        for (int e = 0; e < 4; e++) {
#pragma unroll
            for (int c = 0; c < 2; c++) {           // h-part: A-k 0..63 -> W row 40+k
                F8 hi, lo;
#pragma unroll
                for (int i = 0; i < 8; i++) {
                    int k = 32 * c + ((i >> 2) << 4) + 4 * g + (i & 3);   // 0..63
                    float wv = Wc[(40 + k) * 256 + 64 * e];
                    _Float16 hv = (_Float16)wv;
                    hi.e[i] = hv;
                    lo.e[i] = (_Float16)(wv - (float)hv);
                }
                Bhh[e][c] = hi.v; Bhl[e][c] = lo.v;
            }
#pragma unroll
            for (int c = 0; c < 2; c++) {           // x-part: A-k 64..103 -> W row k-64
                F8 hi;
#pragma unroll
                for (int i = 0; i < 8; i++) {
                    int d = 32 * c + ((i >> 2) << 4) + 4 * g + (i & 3);   // 0..63
                    float wv = (d < DXT) ? Wc[d * 256 + 64 * e] : 0.0f;
                    hi.e[i] = (_Float16)wv;
                }
                Bxh[e][c] = hi.v;
            }
        }
    }

    const float bI = b[u], bJ = b[HDIM + u], bF = b[2 * HDIM + u], bO = b[3 * HDIM + u];
    const float wdec = Wdec[u];
    const float bdec = bdec_p[0];

    // zero both A buffers (h0 = 0, pad = 0)
    for (int i = tid; i < 2 * NB * APAD; i += 256) {
        ((_Float16*)Ahi)[i] = (_Float16)0.0f;
        ((_Float16*)Alo)[i] = (_Float16)0.0f;
    }
    __syncthreads();

    float xv[3];
    auto loadx = [&](int t) {
#pragma unroll
        for (int p = 0; p < 3; p++) {
            int idx = tid + 256 * p;
            float v = 0.0f;
            if (idx < NELM) {
                int s = idx / DXT;
                int d = idx - s * DXT;
                v = (d < OBS) ? obss[((size_t)(n0 + s) * T_STEPS + t) * OBS + d]
                              : actions[((size_t)(n0 + s) * T_STEPS + t) * ACTD + (d - OBS)];
            }
            xv[p] = v;
        }
    };
    auto storex = [&](int buf) {
#pragma unroll
        for (int p = 0; p < 3; p++) {
            int idx = tid + 256 * p;
            if (idx < NELM) {
                int s = idx / DXT;
                int d = idx - s * DXT;
                Ahi[buf][s * APAD + HDIM + d] = (_Float16)xv[p];
            }
        }
    };

    loadx(0);
    storex(0);                 // buf0 = [h0=0 | x0]; loop-top barrier publishes it

    float cr[4] = {0.f, 0.f, 0.f, 0.f};

#pragma unroll 2
    for (int t = 0; t < T_STEPS; ++t) {
        const int cb  = t & 1;
        const int nb2 = cb ^ 1;
        __syncthreads();       // buf[cb] (h_t-1, x_t) and partb[nb2] complete

        if (t > 0 && tid < 16) {
            float o = partb[nb2][tid] + partb[nb2][16 + tid] +
                      partb[nb2][32 + tid] + partb[nb2][48 + tid] + bdec;
            out[(size_t)(t - 1) * NSEQ + n0 + tid] = o;
        }
        if (t + 1 < T_STEPS) loadx(t + 1);   // prefetch under MFMA/update

        const _Float16* Ah = Ahi[cb];
        const _Float16* Al = Alo[cb];
        f16x8 ahh0 = ldfrag(Ah, m, g, 0);
        f16x8 ahh1 = ldfrag(Ah, m, g, 32);
        f16x8 ahl0 = ldfrag(Al, m, g, 0);
        f16x8 ahl1 = ldfrag(Al, m, g, 32);
        f16x8 ax0  = ldfrag(Ah, m, g, 64);
        f16x8 ax1  = ldfrag(Ah, m, g, 96);

        f32x4 acc[4];
#pragma unroll
        for (int e = 0; e < 4; e++) {
            f32x4 a = {0.f, 0.f, 0.f, 0.f};
            // h-part, split precision: Ahi*Bhi + Alo*Bhi + Ahi*Blo
            a = __builtin_amdgcn_mfma_f32_16x16x32_f16(ahh0, Bhh[e][0], a, 0, 0, 0);
            a = __builtin_amdgcn_mfma_f32_16x16x32_f16(ahl0, Bhh[e][0], a, 0, 0, 0);
            a = __builtin_amdgcn_mfma_f32_16x16x32_f16(ahh0, Bhl[e][0], a, 0, 0, 0);
            a = __builtin_amdgcn_mfma_f32_16x16x32_f16(ahh1, Bhh[e][1], a, 0, 0, 0);
            a = __builtin_amdgcn_mfma_f32_16x16x32_f16(ahl1, Bhh[e][1], a, 0, 0, 0);
            a = __builtin_amdgcn_mfma_f32_16x16x32_f16(ahh1, Bhl[e][1], a, 0, 0, 0);
            // x-part, plain f16 (feed-forward, error does not compound)
            a = __builtin_amdgcn_mfma_f32_16x16x32_f16(ax0, Bxh[e][0], a, 0, 0, 0);
            a = __builtin_amdgcn_mfma_f32_16x16x32_f16(ax1, Bxh[e][1], a, 0, 0, 0);
            acc[e] = a;
        }

        // in-register LSTM update: lane holds gates i,j,f,o for (seq 4g+rr, unit u)
        float p4[4];
#pragma unroll
        for (int rr = 0; rr < 4; rr++) {
            float gi = acc[0][rr] + bI;
            float gj = acc[1][rr] + bJ;
            float gf = acc[2][rr] + bF;
            float go = acc[3][rr] + bO;
            float c  = cr[rr] * fsig(gf + 1.0f) + fsig(gi) * ftanh(gj);
            cr[rr] = c;
            float h  = ftanh(c) * fsig(go);
            int s = 4 * g + rr;
            _Float16 hh = (_Float16)h;
            Ahi[nb2][s * APAD + u] = hh;
            Alo[nb2][s * APAD + u] = (_Float16)(h - (float)hh);
            p4[rr] = h * wdec;
        }
        // decode partial: reduce over this wave's 16 units
#pragma unroll
        for (int rr = 0; rr < 4; rr++) {
            float pv = p4[rr];
            pv += __shfl_xor(pv, 1);
            pv += __shfl_xor(pv, 2);
            pv += __shfl_xor(pv, 4);
            pv += __shfl_xor(pv, 8);
            if (m == 0) partb[cb][w * 16 + 4 * g + rr] = pv;
        }
        if (t + 1 < T_STEPS) storex(nb2);    // x_{t+1} into next buffer
    }

    __syncthreads();
    if (tid < 16) {
        float o = partb[1][tid] + partb[1][16 + tid] +
                  partb[1][32 + tid] + partb[1][48 + tid] + bdec;
        out[(size_t)(T_STEPS - 1) * NSEQ + n0 + tid] = o;
    }
}

extern "C" void kernel_launch(void* const* d_in, const int* in_sizes, int n_in,
                              void* d_out, int out_size, void* d_ws, size_t ws_size,
                              hipStream_t stream) {
    (void)in_sizes; (void)n_in; (void)d_ws; (void)ws_size; (void)out_size;
    const float* obss    = (const float*)d_in[0];
    const float* actions = (const float*)d_in[1];
    const float* W       = (const float*)d_in[2];
    const float* b       = (const float*)d_in[3];
    const float* Wdec    = (const float*)d_in[4];
    const float* bdec    = (const float*)d_in[5];
    float* out = (float*)d_out;
    lstm_fused<<<dim3(NSEQ / NB), dim3(256), 0, stream>>>(obss, actions, W, b, Wdec, bdec, out);
}

// Round 2
// 318.182 us; speedup vs baseline: 1.2277x; 1.2277x over previous
//
#include <hip/hip_runtime.h>
#include <cstddef>

#define T_STEPS 256
#define OBS     32
#define ACTD    8
#define HDIM    64
#define NB      16      // sequences per block
#define HPAD    72      // h row stride in f16 (144 B: 16B-aligned, bank-staggered)
#define NSEQ    4096

typedef _Float16 f16x8 __attribute__((ext_vector_type(8)));
typedef float    f32x4 __attribute__((ext_vector_type(4)));

union F8 { f16x8 v; _Float16 e[8]; };

__device__ __forceinline__ float fsig(float x) {
    return __builtin_amdgcn_rcpf(1.0f + __expf(-x));
}
__device__ __forceinline__ float ftanh(float x) {
    return 1.0f - 2.0f * __builtin_amdgcn_rcpf(__expf(2.0f * x) + 1.0f);
}

__global__ __launch_bounds__(512, 2)
void lstm_fused(const float* __restrict__ obss, const float* __restrict__ actions,
                const float* __restrict__ W, const float* __restrict__ b,
                const float* __restrict__ Wdec, const float* __restrict__ bdec_p,
                float* __restrict__ out)
{
    // h stored unit-permuted: unit u lives at column phi(u) so each A-frag is one b128
    __shared__ __align__(16) _Float16 Ahi[2][NB * HPAD];
    __shared__ __align__(16) _Float16 Alo[2][NB * HPAD];
    __shared__ float partb[2][NB][8];     // [buf][seq][wave] decode partials

    const int tid  = threadIdx.x;
    const int w    = tid >> 6;            // wave 0..7
    const int lane = tid & 63;
    const int g    = lane >> 4;           // k-group 0..3
    const int m    = lane & 15;
    const int q    = m & 7;
    const int hb   = m >> 3;              // which gate of the tile's pair
    const int v    = 8 * w + q;           // hidden unit this lane owns
    const int n0   = blockIdx.x * NB;
    // phi(u) = (u&3) + 4*((u>>4)&1) + 8*((u>>2)&3) + 32*(u>>5)
    const int phiv = (v & 3) + ((v >> 4) & 1) * 4 + ((v >> 2) & 3) * 8 + (v >> 5) * 32;
    const int s0   = 4 * g + 2 * hb;      // first of two seqs this lane updates

    // ---- one-time: W fragments in registers. Tile e2: cols 64*(2e2+hb)+v ----
    f16x8 Bhh[2][2], Bhl[2][2], Bxf[2][2];
#pragma unroll
    for (int e2 = 0; e2 < 2; e2++) {
        const float* Wc = W + 64 * (2 * e2 + hb) + v;
#pragma unroll
        for (int c = 0; c < 2; c++) {
            F8 hi, lo;
#pragma unroll
            for (int i = 0; i < 8; i++) {
                int k = 32 * c + ((i >> 2) << 4) + 4 * g + (i & 3);   // 0..63
                float wv = Wc[(40 + k) * 256];
                hi.e[i] = (_Float16)wv;
                lo.e[i] = (_Float16)(wv - (float)hi.e[i]);
            }
            Bhh[e2][c] = hi.v; Bhl[e2][c] = lo.v;
        }
#pragma unroll
        for (int c = 0; c < 2; c++) {
            F8 bx;
#pragma unroll
            for (int i = 0; i < 8; i++) {
                int d = 32 * c + ((i >> 2) << 4) + 4 * g + (i & 3);
                bx.e[i] = (d < OBS + ACTD) ? (_Float16)Wc[d * 256] : (_Float16)0.0f;
            }
            Bxf[e2][c] = bx.v;
        }
    }
    const float bI = b[v], bJ = b[HDIM + v], bF = b[2 * HDIM + v], bO = b[3 * HDIM + v];
    const float wd = Wdec[v];
    const float bd = bdec_p[0];

    for (int i = tid; i < 2 * NB * HPAD; i += 512) {
        (&Ahi[0][0])[i] = (_Float16)0.0f;
        (&Alo[0][0])[i] = (_Float16)0.0f;
    }

    // per-lane x prefetch: A row m, obs dims {4g..4g+3, 16+4g..19+4g}, act dims {4g..} (g<2)
    f32x4 xo0 = {0,0,0,0}, xo1 = {0,0,0,0}, xa = {0,0,0,0};
    auto loadx = [&](int t) {
        const float* pb = obss + ((size_t)(n0 + m) * T_STEPS + t) * OBS + 4 * g;
        xo0 = *(const f32x4*)pb;
        xo1 = *(const f32x4*)(pb + 16);
        if (g < 2)
            xa = *(const f32x4*)(actions + ((size_t)(n0 + m) * T_STEPS + t) * ACTD + 4 * g);
    };
    loadx(0);
    float cr0 = 0.f, cr1 = 0.f;

#pragma unroll 2
    for (int t = 0; t < T_STEPS; ++t) {
        const int cb  = t & 1;
        const int nb2 = cb ^ 1;
        // LDS-only barrier: x prefetch (vmcnt) may span it
        asm volatile("s_waitcnt lgkmcnt(0)\n\ts_barrier" ::: "memory");

        if (t > 0 && tid < 16) {
            float o = bd;
#pragma unroll
            for (int k2 = 0; k2 < 8; k2++) o += partb[nb2][tid][k2];
            out[(size_t)(t - 1) * NSEQ + n0 + tid] = o;
        }

        // current-step x frags from prefetched regs
        F8 a0u, a1u;
#pragma unroll
        for (int i = 0; i < 4; i++) { a0u.e[i] = (_Float16)xo0[i]; a0u.e[4 + i] = (_Float16)xo1[i]; }
#pragma unroll
        for (int i = 0; i < 4; i++) { a1u.e[i] = (g < 2) ? (_Float16)xa[i] : (_Float16)0.0f; a1u.e[4 + i] = (_Float16)0.0f; }
        f16x8 ax0 = a0u.v, ax1 = a1u.v;
        if (t + 1 < T_STEPS) loadx(t + 1);   // prefetch next step

        const _Float16* Ah = Ahi[cb];
        const _Float16* Al = Alo[cb];
        f16x8 hh0 = *(const f16x8*)(Ah + m * HPAD + 8 * g);
        f16x8 hh1 = *(const f16x8*)(Ah + m * HPAD + 32 + 8 * g);
        f16x8 hl0 = *(const f16x8*)(Al + m * HPAD + 8 * g);
        f16x8 hl1 = *(const f16x8*)(Al + m * HPAD + 32 + 8 * g);

        // 4 independent 4-deep MFMA chains, then 2 vector adds
        f32x4 z = {0.f, 0.f, 0.f, 0.f};
        f32x4 a0A = z, a0B = z, a1A = z, a1B = z;
        a0A = __builtin_amdgcn_mfma_f32_16x16x32_f16(hh0, Bhh[0][0], a0A, 0, 0, 0);
        a0B = __builtin_amdgcn_mfma_f32_16x16x32_f16(hh1, Bhh[0][1], a0B, 0, 0, 0);
        a1A = __builtin_amdgcn_mfma_f32_16x16x32_f16(hh0, Bhh[1][0], a1A, 0, 0, 0);
        a1B = __builtin_amdgcn_mfma_f32_16x16x32_f16(hh1, Bhh[1][1], a1B, 0, 0, 0);
        a0A = __builtin_amdgcn_mfma_f32_16x16x32_f16(hl0, Bhh[0][0], a0A, 0, 0, 0);
        a0B = __builtin_amdgcn_mfma_f32_16x16x32_f16(hl1, Bhh[0][1], a0B, 0, 0, 0);
        a1A = __builtin_amdgcn_mfma_f32_16x16x32_f16(hl0, Bhh[1][0], a1A, 0, 0, 0);
        a1B = __builtin_amdgcn_mfma_f32_16x16x32_f16(hl1, Bhh[1][1], a1B, 0, 0, 0);
        a0A = __builtin_amdgcn_mfma_f32_16x16x32_f16(hh0, Bhl[0][0], a0A, 0, 0, 0);
        a0B = __builtin_amdgcn_mfma_f32_16x16x32_f16(hh1, Bhl[0][1], a0B, 0, 0, 0);
        a1A = __builtin_amdgcn_mfma_f32_16x16x32_f16(hh0, Bhl[1][0], a1A, 0, 0, 0);
        a1B = __builtin_amdgcn_mfma_f32_16x16x32_f16(hh1, Bhl[1][1], a1B, 0, 0, 0);
        a0A = __builtin_amdgcn_mfma_f32_16x16x32_f16(ax0, Bxf[0][0], a0A, 0, 0, 0);
        a0B = __builtin_amdgcn_mfma_f32_16x16x32_f16(ax1, Bxf[0][1], a0B, 0, 0, 0);
        a1A = __builtin_amdgcn_mfma_f32_16x16x32_f16(ax0, Bxf[1][0], a1A, 0, 0, 0);
        a1B = __builtin_amdgcn_mfma_f32_16x16x32_f16(ax1, Bxf[1][1], a1B, 0, 0, 0);
        f32x4 a0 = a0A + a0B;   // gate (hb? j : i) for seqs 4g+0..3
        f32x4 a1 = a1A + a1B;   // gate (hb? o : f)

        // 4-shfl gate exchange with partner lane (m^8): each lane sends the
        // rr-half its partner needs, receives the gate it lacks
        float r1 = __shfl_xor(hb ? a0[0] : a0[2], 8);
        float r2 = __shfl_xor(hb ? a0[1] : a0[3], 8);
        float r3 = __shfl_xor(hb ? a1[0] : a1[2], 8);
        float r4 = __shfl_xor(hb ? a1[1] : a1[3], 8);

        float gi0 = hb ? r1 : a0[0], gj0 = hb ? a0[2] : r1;
        float gf0 = hb ? r3 : a1[0], go0 = hb ? a1[2] : r3;
        float gi1 = hb ? r2 : a0[1], gj1 = hb ? a0[3] : r2;
        float gf1 = hb ? r4 : a1[1], go1 = hb ? a1[3] : r4;

        float c0 = cr0 * fsig(gf0 + bF + 1.0f) + fsig(gi0 + bI) * ftanh(gj0 + bJ);
        cr0 = c0;
        float h0 = ftanh(c0) * fsig(go0 + bO);
        float c1 = cr1 * fsig(gf1 + bF + 1.0f) + fsig(gi1 + bI) * ftanh(gj1 + bJ);
        cr1 = c1;
        float h1 = ftanh(c1) * fsig(go1 + bO);

        _Float16 h0h = (_Float16)h0;
        Ahi[nb2][s0 * HPAD + phiv]       = h0h;
        Alo[nb2][s0 * HPAD + phiv]       = (_Float16)(h0 - (float)h0h);
        _Float16 h1h = (_Float16)h1;
        Ahi[nb2][(s0 + 1) * HPAD + phiv] = h1h;
        Alo[nb2][(s0 + 1) * HPAD + phiv] = (_Float16)(h1 - (float)h1h);

        // decode partial: reduce over this wave's 8 units (lane bits 0..2)
        float p0 = h0 * wd, p1 = h1 * wd;
        p0 += __shfl_xor(p0, 1); p0 += __shfl_xor(p0, 2); p0 += __shfl_xor(p0, 4);
        p1 += __shfl_xor(p1, 1); p1 += __shfl_xor(p1, 2); p1 += __shfl_xor(p1, 4);
        if (q == 0) {
            partb[cb][s0][w]     = p0;
            partb[cb][s0 + 1][w] = p1;
        }
    }

    __syncthreads();
    if (tid < 16) {
        float o = bd;
#pragma unroll
        for (int k2 = 0; k2 < 8; k2++) o += partb[1][tid][k2];
        out[(size_t)(T_STEPS - 1) * NSEQ + n0 + tid] = o;
    }
}

extern "C" void kernel_launch(void* const* d_in, const int* in_sizes, int n_in,
                              void* d_out, int out_size, void* d_ws, size_t ws_size,
                              hipStream_t stream) {
    (void)in_sizes; (void)n_in; (void)d_ws; (void)ws_size; (void)out_size;
    const float* obss    = (const float*)d_in[0];
    const float* actions = (const float*)d_in[1];
    const float* W       = (const float*)d_in[2];
    const float* b       = (const float*)d_in[3];
    const float* Wdec    = (const float*)d_in[4];
    const float* bdec    = (const float*)d_in[5];
    float* out = (float*)d_out;
    lstm_fused<<<dim3(NSEQ / NB), dim3(512), 0, stream>>>(obss, actions, W, b, Wdec, bdec, out);
}

// Round 3
// 282.448 us; speedup vs baseline: 1.3830x; 1.1265x over previous
//
#include <hip/hip_runtime.h>
#include <cstddef>

#define T_STEPS 256
#define OBS     32
#define ACTD    8
#define NB      8       // sequences per block
#define HPAD    72      // h row stride in f16 (144 B)
#define NSEQ    4096

typedef _Float16 f16x8 __attribute__((ext_vector_type(8)));
typedef float    f32x4 __attribute__((ext_vector_type(4)));

union F8 { f16x8 v; _Float16 e[8]; };

__device__ __forceinline__ float fsig(float x) {
    return __builtin_amdgcn_rcpf(1.0f + __expf(-x));
}
__device__ __forceinline__ float ftanh(float x) {
    return 1.0f - 2.0f * __builtin_amdgcn_rcpf(__expf(2.0f * x) + 1.0f);
}

// single-instruction cross-lane add via DPP (replaces ds_bpermute shuffles)
template<int CTRL>
__device__ __forceinline__ float dppadd(float x) {
    int y = __builtin_amdgcn_update_dpp(0, __builtin_bit_cast(int, x), CTRL, 0xF, 0xF, true);
    return x + __builtin_bit_cast(float, y);
}
#define DPP_XOR1 0xB1   // quad_perm [1,0,3,2]
#define DPP_XOR2 0x4E   // quad_perm [2,3,0,1]
#define DPP_MIR8 0x141  // row_half_mirror (xor4 after lower bits reduced)
#define DPP_ROR8 0x128  // row_ror:8 == xor8 within 16-lane row

__global__ __launch_bounds__(256, 2)
void lstm_fused(const float* __restrict__ obss, const float* __restrict__ actions,
                const float* __restrict__ W, const float* __restrict__ b,
                const float* __restrict__ Wdec, const float* __restrict__ bdec_p,
                float* __restrict__ out)
{
    // A rows (MFMA M) : row 4a+b (b<2) = seq 2a+b; rows with (r&3)>=2 are zero.
    // h storage indexed by seq (8 rows), unit permuted by phi for contiguous b128 frags.
    __shared__ __align__(16) _Float16 Ahi[2][NB * HPAD];
    __shared__ __align__(16) _Float16 Alo[2][NB * HPAD];
    __shared__ __align__(16) float    partb[2][NB][4];   // [buf][seq][wave]

    const int tid  = threadIdx.x;
    const int w    = tid >> 6;            // wave 0..3
    const int lane = tid & 63;
    const int g    = lane >> 4;           // k-group / C-row-group
    const int m    = lane & 15;           // A-row (as frag provider) / unit col
    const int u    = 16 * w + m;          // hidden unit this lane owns (all 4 gates)
    const int n0   = blockIdx.x * NB;
    const bool act = (m & 3) < 2;         // this lane provides a real A row
    const int rho  = 2 * (m >> 2) + (m & 1);   // seq index of that row
    // phi(u) = (u&3) + 4*((u>>4)&1) + 8*((u>>2)&3) + 32*(u>>5)
    const int phiu = (m & 3) + 4 * (w & 1) + 8 * (m >> 2) + 32 * (w >> 1);

    // ---- one-time: W fragments in registers (hi/lo split for h-part) ----
    // wave w owns gate cols 64e + u for e=0..3 (i,j,f,o of unit u stay in-lane)
    f16x8 Bhh[4][2], Bhl[4][2], Bxf[4][2];
    {
        const float* Wc = W + u;
#pragma unroll
        for (int e = 0; e < 4; e++) {
#pragma unroll
            for (int c = 0; c < 2; c++) {
                F8 hi, lo, bx;
#pragma unroll
                for (int i = 0; i < 8; i++) {
                    int k = 32 * c + 16 * (i >> 2) + 4 * g + (i & 3);  // 0..63
                    float wv = Wc[(40 + k) * 256 + 64 * e];
                    hi.e[i] = (_Float16)wv;
                    lo.e[i] = (_Float16)(wv - (float)hi.e[i]);
                    bx.e[i] = (k < OBS + ACTD) ? (_Float16)Wc[k * 256 + 64 * e]
                                               : (_Float16)0.0f;
                }
                Bhh[e][c] = hi.v; Bhl[e][c] = lo.v; Bxf[e][c] = bx.v;
            }
        }
    }
    const float bI = b[u], bJ = b[64 + u], bF1 = b[128 + u] + 1.0f, bO = b[192 + u];
    const float wd = Wdec[u];
    const float bd = bdec_p[0];

    for (int i = tid; i < NB * HPAD; i += 256) {
        Ahi[0][i] = (_Float16)0.0f;  Ahi[1][i] = (_Float16)0.0f;
        Alo[0][i] = (_Float16)0.0f;  Alo[1][i] = (_Float16)0.0f;
    }

    // per-lane x prefetch (active lanes only): seq rho, obs dims {4g..+3, 16+4g..+3}, act dims 4g.. (g<2)
    f32x4 xo0 = {0,0,0,0}, xo1 = {0,0,0,0}, xa = {0,0,0,0};
    auto loadx = [&](int t) {
        if (act) {
            const float* pb = obss + ((size_t)(n0 + rho) * T_STEPS + t) * OBS + 4 * g;
            xo0 = *(const f32x4*)pb;
            xo1 = *(const f32x4*)(pb + 16);
            if (g < 2)
                xa = *(const f32x4*)(actions + ((size_t)(n0 + rho) * T_STEPS + t) * ACTD + 4 * g);
        }
    };
    loadx(0);
    float cr0 = 0.f, cr1 = 0.f;

#pragma unroll 2
    for (int t = 0; t < T_STEPS; ++t) {
        const int cb  = t & 1;
        const int nb2 = cb ^ 1;
        // LDS-only barrier: x prefetch (vmcnt) may span it
        asm volatile("s_waitcnt lgkmcnt(0)\n\ts_barrier" ::: "memory");

        if (t > 0 && tid < NB) {
            f32x4 pv = *(const f32x4*)&partb[nb2][tid][0];
            out[(size_t)(t - 1) * NSEQ + n0 + tid] = pv[0] + pv[1] + pv[2] + pv[3] + bd;
        }

        // current-step x frags from prefetched regs (zeros for inactive rows)
        F8 a0u, a1u;
#pragma unroll
        for (int i = 0; i < 4; i++) { a0u.e[i] = (_Float16)xo0[i]; a0u.e[4 + i] = (_Float16)xo1[i]; }
#pragma unroll
        for (int i = 0; i < 4; i++) { a1u.e[i] = (_Float16)xa[i];  a1u.e[4 + i] = (_Float16)0.0f; }
        f16x8 ax0 = a0u.v, ax1 = a1u.v;
        if (t + 1 < T_STEPS) loadx(t + 1);

        // h fragments (active rows only; inactive rows contribute zero)
        const f16x8 ZH = {0,0,0,0,0,0,0,0};
        f16x8 hh0 = ZH, hh1 = ZH, hl0 = ZH, hl1 = ZH;
        if (act) {
            const _Float16* bh = &Ahi[cb][rho * HPAD];
            const _Float16* bl = &Alo[cb][rho * HPAD];
            hh0 = *(const f16x8*)(bh + 8 * g);
            hh1 = *(const f16x8*)(bh + 32 + 8 * g);
            hl0 = *(const f16x8*)(bl + 8 * g);
            hl1 = *(const f16x8*)(bl + 32 + 8 * g);
        }

        // 4 gate tiles, 2 chains each (c=0 / c=1), x-product starts the chain
        f32x4 acc[4];
#pragma unroll
        for (int e = 0; e < 4; e++) {
            f32x4 z = {0.f, 0.f, 0.f, 0.f};
            f32x4 aA = __builtin_amdgcn_mfma_f32_16x16x32_f16(ax0, Bxf[e][0], z, 0, 0, 0);
            f32x4 aB = __builtin_amdgcn_mfma_f32_16x16x32_f16(ax1, Bxf[e][1], z, 0, 0, 0);
            aA = __builtin_amdgcn_mfma_f32_16x16x32_f16(hh0, Bhh[e][0], aA, 0, 0, 0);
            aB = __builtin_amdgcn_mfma_f32_16x16x32_f16(hh1, Bhh[e][1], aB, 0, 0, 0);
            aA = __builtin_amdgcn_mfma_f32_16x16x32_f16(hl0, Bhh[e][0], aA, 0, 0, 0);
            aB = __builtin_amdgcn_mfma_f32_16x16x32_f16(hl1, Bhh[e][1], aB, 0, 0, 0);
            aA = __builtin_amdgcn_mfma_f32_16x16x32_f16(hh0, Bhl[e][0], aA, 0, 0, 0);
            aB = __builtin_amdgcn_mfma_f32_16x16x32_f16(hh1, Bhl[e][1], aB, 0, 0, 0);
            acc[e] = aA + aB;
        }

        // cell update: lane owns unit u for seqs 2g+0, 2g+1 (C rows 4g+0, 4g+1)
#pragma unroll
        for (int j = 0; j < 2; j++) {
            float gi = acc[0][j] + bI;
            float gj = acc[1][j] + bJ;
            float gf = acc[2][j] + bF1;
            float go = acc[3][j] + bO;
            float& cr = j ? cr1 : cr0;
            float c = cr * fsig(gf) + fsig(gi) * ftanh(gj);
            cr = c;
            float h = ftanh(c) * fsig(go);
            _Float16 hhv = (_Float16)h;
            const int s = 2 * g + j;
            Ahi[nb2][s * HPAD + phiu] = hhv;
            Alo[nb2][s * HPAD + phiu] = (_Float16)(h - (float)hhv);
            // decode partial: reduce over the wave's 16 units (lane bits 0..3) via DPP
            float p = h * wd;
            p = dppadd<DPP_XOR1>(p);
            p = dppadd<DPP_XOR2>(p);
            p = dppadd<DPP_MIR8>(p);
            p = dppadd<DPP_ROR8>(p);
            if (m == 0) partb[cb][s][w] = p;
        }
    }

    __syncthreads();
    if (tid < NB) {
        f32x4 pv = *(const f32x4*)&partb[(T_STEPS - 1) & 1][tid][0];
        out[(size_t)(T_STEPS - 1) * NSEQ + n0 + tid] = pv[0] + pv[1] + pv[2] + pv[3] + bd;
    }
}

extern "C" void kernel_launch(void* const* d_in, const int* in_sizes, int n_in,
                              void* d_out, int out_size, void* d_ws, size_t ws_size,
                              hipStream_t stream) {
    (void)in_sizes; (void)n_in; (void)d_ws; (void)ws_size; (void)out_size;
    const float* obss    = (const float*)d_in[0];
    const float* actions = (const float*)d_in[1];
    const float* W       = (const float*)d_in[2];
    const float* b       = (const float*)d_in[3];
    const float* Wdec    = (const float*)d_in[4];
    const float* bdec    = (const float*)d_in[5];
    float* out = (float*)d_out;
    lstm_fused<<<dim3(NSEQ / NB), dim3(256), 0, stream>>>(obss, actions, W, b, Wdec, bdec, out);
}